// Round 7
// baseline (266.937 us; speedup 1.0000x reference)
//
#include <hip/hip_runtime.h>
#include <hip/hip_bf16.h>
#include <stdint.h>

// QuantizedLinear: out[16,11008] = x[16,4096] @ ((W - zp)*scale)^T
// HARNESS NOTE: W arrives as a 180 MB int32 buffer. Roofline = 180 MB /
// 6.3 TB/s ~ 29 us; harness fillBuffer resets (~208 us/iter, 86% peak) are
// untouchable context. qgemm read BW to date: R0 4.3 -> R3/R6 ~5.0 TB/s.
//
// Ladder: R3 (+7us): 256B->1KB granule. R4 null: latency structure
// irrelevant. R5 regression: whole-slab test CONFOUNDED (2 blocks/CU ->
// 176-block batch tail, probable >128-VGPR spill). R6 ~null: 1KB->4KB
// granule is flat.
//
// R7: R5's stream-count theory, de-confounded. 8 rows/block (grid 1376),
// slab = 128 KB contiguous staged in strict linear order (4 KB/instr).
// ~1k long linear streams chip-wide instead of 11008 row-streams.
// LDS 35 KB (single 32 KB packed buffer) -> 4 blocks/CU; staging in 4
// batches of 8 v4i (unroll 1 + sched_barrier) keeps VGPR < 128 -> 16
// waves/CU, 1024 co-resident, 352-block tail still holds ~11 MB in
// flight (>> 2.4 MB Little's law) so tail runs at full BW.
// B-frag: rows n&7 (lanes 8-15 broadcast), swizzle slot^row. Numerics
// identical to R3/R6 (same quant, same 4-way K reduction order).

#define M_TOK 16
#define K_DIM 4096
#define N_OUT 11008

typedef int v4i __attribute__((ext_vector_type(4)));

// ---------------- Kernel 1: per-token quantization of x ----------------
// ws layout: xh[16*4096] | xl[16*4096] | s1[16] | sumx[16]
__global__ __launch_bounds__(256) void quant_x_kernel(
    const float* __restrict__ x, int8_t* __restrict__ xh,
    int8_t* __restrict__ xl, float* __restrict__ s1_out,
    float* __restrict__ sumx_out) {
  const int t = blockIdx.x;      // token
  const int tid = threadIdx.x;   // 256 threads, 16 consecutive elems each
  const float4* xv = (const float4*)(x + (long)t * K_DIM) + tid * 4;

  float vals[16];
  float m = 0.0f, s = 0.0f;
#pragma unroll
  for (int j = 0; j < 4; ++j) {
    float4 f = xv[j];
    vals[j * 4 + 0] = f.x; vals[j * 4 + 1] = f.y;
    vals[j * 4 + 2] = f.z; vals[j * 4 + 3] = f.w;
    m = fmaxf(m, fmaxf(fmaxf(fabsf(f.x), fabsf(f.y)),
                       fmaxf(fabsf(f.z), fabsf(f.w))));
    s += f.x + f.y + f.z + f.w;
  }
#pragma unroll
  for (int off = 32; off > 0; off >>= 1) {
    m = fmaxf(m, __shfl_xor(m, off));
    s += __shfl_xor(s, off);
  }
  __shared__ float lm[4], ls[4];
  const int w = tid >> 6;
  if ((tid & 63) == 0) { lm[w] = m; ls[w] = s; }
  __syncthreads();
  m = fmaxf(fmaxf(lm[0], lm[1]), fmaxf(lm[2], lm[3]));
  s = ls[0] + ls[1] + ls[2] + ls[3];

  const float s1 = (m > 0.0f) ? (m * (1.0f / 127.0f)) : 1.0f;
  const float inv = 1.0f / s1;
  if (tid == 0) { s1_out[t] = s1; sumx_out[t] = s; }

  int hq[16], lq[16];
#pragma unroll
  for (int j = 0; j < 16; ++j) {
    float xf = vals[j];
    float h = rintf(xf * inv);
    h = fminf(fmaxf(h, -127.0f), 127.0f);
    float resid = xf - h * s1;
    float l = rintf(resid * inv * 256.0f);
    l = fminf(fmaxf(l, -128.0f), 127.0f);
    hq[j] = (int)h;
    lq[j] = (int)l;
  }
  int4 hv, lv;
  int* hp = (int*)&hv;
  int* lp = (int*)&lv;
#pragma unroll
  for (int d = 0; d < 4; ++d) {
    uint32_t hw = 0, lw = 0;
#pragma unroll
    for (int j = 0; j < 4; ++j) {
      hw |= (uint32_t)(hq[d * 4 + j] & 0xff) << (8 * j);
      lw |= (uint32_t)(lq[d * 4 + j] & 0xff) << (8 * j);
    }
    hp[d] = (int)hw;
    lp[d] = (int)lw;
  }
  ((int4*)xh)[(long)t * 256 + tid] = hv;
  ((int4*)xl)[(long)t * 256 + tid] = lv;
}

// ---------------- Kernel 2: linear-slab i8 MFMA GEMM, 8 rows/block --------
// Grid = 1376 blocks x 256 thr (4 waves). Block owns 8 output rows = one
// contiguous 128 KB slab of W.
// Phase 1: stage slab in LINEAR order (each instr 4 KB contiguous), pack
//   int32->int8, write XOR-swizzled LDS. 4 batches of 8 v4i/thread.
// Phase 2 (one barrier): wave w computes K quarter [w*1024,+1024):
//   16 x { ds_read_b128 B-frag (rows n&7) + hi/lo MFMA }, barrier-free.
// Epilogue: 4-way K reduction in LDS, store 8 cols.
__global__ __launch_bounds__(256) void qgemm_kernel(
    const int* __restrict__ W, const int8_t* __restrict__ xh,
    const int8_t* __restrict__ xl, const float* __restrict__ s1,
    const float* __restrict__ sumx, const float* __restrict__ scale_p,
    const int* __restrict__ zp_p, float* __restrict__ out) {
  const int tid = threadIdx.x;
  const int lane = tid & 63;
  const int w = tid >> 6;          // wave id = K quarter
  const int obase = blockIdx.x * 8;
  const int n = lane & 15;         // token (A row) / output col id
  const int g = lane >> 4;         // k sub-group within 64-k window
  const int brow = n & 7;          // W row within block (lanes 8-15 dup)

  __shared__ uint32_t wbuf[8 * 1024];   // packed int8 slab, swizzled
  __shared__ float red[4][16 * 9];

  // ---- Phase 1: linear slab stage ----
  // slab = 8 rows x 4096 int32 = 32768 int32 = 8192 v4i, contiguous.
  // Batch b, sub i: thread reads v4i at [b*2048 + i*256 + tid]
  //   -> each instruction covers 4 KB contiguous; batches advance linearly.
  const v4i* slab = (const v4i*)(W + (long)obase * K_DIM);
#pragma unroll 1
  for (int b = 0; b < 4; ++b) {
    v4i q[8];
#pragma unroll
    for (int i = 0; i < 8; ++i) q[i] = slab[b * 2048 + i * 256 + tid];
#pragma unroll
    for (int i = 0; i < 8; ++i) {
      const int idx4 = b * 2048 + i * 256 + tid;  // v4i index in slab
      const int row = idx4 >> 10;                 // 1024 v4i per weight row
      const int k4v = idx4 & 1023;                // packed dword idx in row
      uint32_t p = ((uint32_t)q[i].x & 0xffu) |
                   (((uint32_t)q[i].y & 0xffu) << 8) |
                   (((uint32_t)q[i].z & 0xffu) << 16) |
                   (((uint32_t)q[i].w & 0xffu) << 24);
      // Swizzle b128 slot (k4v>>2) with row so phase-2 reads (8 rows, same
      // slot) spread across banks. Write side: 64 consecutive dwords/wave
      // -> 2/bank = free.
      const int wr = (row << 10) | (((k4v >> 2) ^ row) << 2) | (k4v & 3);
      wbuf[wr] = p;
    }
    // Pin batch boundary: stop the compiler hoisting all 32 loads (VGPR).
    __builtin_amdgcn_sched_barrier(0);
  }
  __syncthreads();

  // ---- Phase 2: barrier-free compute ----
  // A fragments (L2-resident x planes): v4i idx = n*256 + w*64 + it*4 + g.
  const v4i* Ah = (const v4i*)xh + n * 256 + w * 64 + g;
  const v4i* Al = (const v4i*)xl + n * 256 + w * 64 + g;
  v4i accH = {0, 0, 0, 0};
  v4i accL = {0, 0, 0, 0};
#pragma unroll
  for (int it = 0; it < 16; ++it) {
    const int slot = w * 64 + it * 4 + g;   // b128 slot within row
    const v4i bfrag =
        *(const v4i*)&wbuf[(brow << 10) | ((slot ^ brow) << 2)];
    accH = __builtin_amdgcn_mfma_i32_16x16x64_i8(Ah[it * 4], bfrag, accH,
                                                 0, 0, 0);
    accL = __builtin_amdgcn_mfma_i32_16x16x64_i8(Al[it * 4], bfrag, accL,
                                                 0, 0, 0);
  }

  // C layout (16x16): col = lane&15 (=W row id; 8-15 duplicate 0-7),
  // row = (lane>>4)*4 + reg (=token). Store only n<8.
#pragma unroll
  for (int r = 0; r < 4; ++r) {
    float f = (float)accH[r] + (float)accL[r] * (1.0f / 256.0f);
    const int t = g * 4 + r;
    if (n < 8) red[w][t * 9 + n] = f;
  }
  __syncthreads();

  if (tid < 128) {
    const int t = tid >> 3;
    const int col = tid & 7;
    const float sum = red[0][t * 9 + col] + red[1][t * 9 + col] +
                      red[2][t * 9 + col] + red[3][t * 9 + col];
    const float sc = scale_p[0];
    const float zp = (float)zp_p[0];
    const float o = sc * (s1[t] * sum) - sc * zp * sumx[t];
    out[(long)t * N_OUT + obase + col] = o;
  }
}

extern "C" void kernel_launch(void* const* d_in, const int* in_sizes, int n_in,
                              void* d_out, int out_size, void* d_ws,
                              size_t ws_size, hipStream_t stream) {
  const float* x = (const float*)d_in[0];
  const int* Wq = (const int*)d_in[1];          // int inputs come as int32
  const float* scale_p = (const float*)d_in[2];
  const int* zp_p = (const int*)d_in[3];
  float* out = (float*)d_out;

  int8_t* xh = (int8_t*)d_ws;
  int8_t* xl = xh + (long)M_TOK * K_DIM;
  float* s1 = (float*)(xl + (long)M_TOK * K_DIM);
  float* sumx = s1 + M_TOK;

  quant_x_kernel<<<M_TOK, 256, 0, stream>>>(x, xh, xl, s1, sumx);
  qgemm_kernel<<<N_OUT / 8, 256, 0, stream>>>(Wq, xh, xl, s1, sumx, scale_p,
                                              zp_p, out);
}

// Round 8
// 255.427 us; speedup vs baseline: 1.0451x; 1.0451x over previous
//
#include <hip/hip_runtime.h>
#include <hip/hip_bf16.h>
#include <stdint.h>

// QuantizedLinear: out[16,11008] = x[16,4096] @ ((W - zp)*scale)^T
// HARNESS NOTE: W arrives as a 180 MB int32 buffer. Roofline = 180 MB /
// 6.3 TB/s ~ 29 us; harness fillBuffer resets (~208 us/iter, 86% peak) are
// untouchable context. qgemm read BW: ~4.8-5.0 TB/s.
//
// FINAL LADDER (best = this kernel, R6, 252.8 us total):
//   R3 (+7us): 256B->1KB row-visit granule via reg-staged packed-LDS tiles.
//   R4 null: counted-vmcnt / deep prefetch — chunk cadence 5500 cy >> 900 cy
//     HBM latency, latency structure irrelevant.
//   R5/R7 regressions: longer-stream designs (stage-all-K, 8-row slabs)
//     trade LDS-co-residency for stream shape and lose both times. The
//     stream-count lever is structurally inaccessible: slab_bytes x
//     blocks/CU <= LDS.
//   R6 (this): chunk K=1024, 4KB sequential per row-visit, full occupancy
//     (37.1 KB LDS, grid-limited 2.69 blocks/CU), lgkm-only barriers.

#define M_TOK 16
#define K_DIM 4096
#define N_OUT 11008

typedef int v4i __attribute__((ext_vector_type(4)));

// ---------------- Kernel 1: per-token quantization of x ----------------
// ws layout: xh[16*4096] | xl[16*4096] | s1[16] | sumx[16]
__global__ __launch_bounds__(256) void quant_x_kernel(
    const float* __restrict__ x, int8_t* __restrict__ xh,
    int8_t* __restrict__ xl, float* __restrict__ s1_out,
    float* __restrict__ sumx_out) {
  const int t = blockIdx.x;      // token
  const int tid = threadIdx.x;   // 256 threads, 16 consecutive elems each
  const float4* xv = (const float4*)(x + (long)t * K_DIM) + tid * 4;

  float vals[16];
  float m = 0.0f, s = 0.0f;
#pragma unroll
  for (int j = 0; j < 4; ++j) {
    float4 f = xv[j];
    vals[j * 4 + 0] = f.x; vals[j * 4 + 1] = f.y;
    vals[j * 4 + 2] = f.z; vals[j * 4 + 3] = f.w;
    m = fmaxf(m, fmaxf(fmaxf(fabsf(f.x), fabsf(f.y)),
                       fmaxf(fabsf(f.z), fabsf(f.w))));
    s += f.x + f.y + f.z + f.w;
  }
#pragma unroll
  for (int off = 32; off > 0; off >>= 1) {
    m = fmaxf(m, __shfl_xor(m, off));
    s += __shfl_xor(s, off);
  }
  __shared__ float lm[4], ls[4];
  const int w = tid >> 6;
  if ((tid & 63) == 0) { lm[w] = m; ls[w] = s; }
  __syncthreads();
  m = fmaxf(fmaxf(lm[0], lm[1]), fmaxf(lm[2], lm[3]));
  s = ls[0] + ls[1] + ls[2] + ls[3];

  const float s1 = (m > 0.0f) ? (m * (1.0f / 127.0f)) : 1.0f;
  const float inv = 1.0f / s1;
  if (tid == 0) { s1_out[t] = s1; sumx_out[t] = s; }

  int hq[16], lq[16];
#pragma unroll
  for (int j = 0; j < 16; ++j) {
    float xf = vals[j];
    float h = rintf(xf * inv);
    h = fminf(fmaxf(h, -127.0f), 127.0f);
    float resid = xf - h * s1;
    float l = rintf(resid * inv * 256.0f);
    l = fminf(fmaxf(l, -128.0f), 127.0f);
    hq[j] = (int)h;
    lq[j] = (int)l;
  }
  int4 hv, lv;
  int* hp = (int*)&hv;
  int* lp = (int*)&lv;
#pragma unroll
  for (int d = 0; d < 4; ++d) {
    uint32_t hw = 0, lw = 0;
#pragma unroll
    for (int j = 0; j < 4; ++j) {
      hw |= (uint32_t)(hq[d * 4 + j] & 0xff) << (8 * j);
      lw |= (uint32_t)(lq[d * 4 + j] & 0xff) << (8 * j);
    }
    hp[d] = (int)hw;
    lp[d] = (int)lw;
  }
  ((int4*)xh)[(long)t * 256 + tid] = hv;
  ((int4*)xl)[(long)t * 256 + tid] = lv;
}

// ---------------- Kernel 2: LDS-staged i8 MFMA GEMM, 4KB-granule chunks ---
// Grid = 688 blocks x 256 thr (4 waves). Block owns 16 output rows, full K.
// Chunk = 1024 k. Per chunk: wave w stages rows 4w..4w+3, 4 KB sequential
// per row (4 x 1KB instructions), packs int32->int8, writes XOR-swizzled
// LDS. Compute: per chunk each wave does 4 x {ds_read_b128 + hi/lo MFMA}
// on its K-quarter. 4 chunks, 2x16KB LDS dbuf, lgkm-only barriers.
__global__ __launch_bounds__(256) void qgemm_kernel(
    const int* __restrict__ W, const int8_t* __restrict__ xh,
    const int8_t* __restrict__ xl, const float* __restrict__ s1,
    const float* __restrict__ sumx, const float* __restrict__ scale_p,
    const int* __restrict__ zp_p, float* __restrict__ out) {
  const int tid = threadIdx.x;
  const int lane = tid & 63;
  const int w = tid >> 6;          // wave id
  const int obase = blockIdx.x * 16;
  const int n = lane & 15;         // output-row (B col) / token (A row)
  const int g = lane >> 4;         // k sub-group within 64-k window
  const int r0 = w * 4;            // first staged row for this wave

  __shared__ uint32_t wbuf[2][16 * 256];  // [buf][row*256 + swz dword]
  __shared__ float red[4][16 * 17];

  // Staging pointers: row base + lane*16B. Chunk c sub-load i reads
  // v4i at [c*256 + i*64] (c*4KB + i*1KB per row).
  const v4i* Wr0 = (const v4i*)(W + (long)(obase + r0 + 0) * K_DIM) + lane;
  const v4i* Wr1 = (const v4i*)(W + (long)(obase + r0 + 1) * K_DIM) + lane;
  const v4i* Wr2 = (const v4i*)(W + (long)(obase + r0 + 2) * K_DIM) + lane;
  const v4i* Wr3 = (const v4i*)(W + (long)(obase + r0 + 3) * K_DIM) + lane;

  // LDS write index (dwords): row r, sub i, lane -> packed dword index
  // p = i*64 + lane; swizzle slot (p>>2) with row&7:
  // idx = r*256 + i*64 + (((lane>>2) ^ (r&7))<<2) + (lane&3).
  int wbase[4];
#pragma unroll
  for (int r = 0; r < 4; ++r) {
    const int row = r0 + r;
    wbase[r] = row * 256 + ((((lane >> 2) ^ (row & 7)) << 2) | (lane & 3));
  }

  // A fragments (L2-resident x planes): v4i idx = n*256 + c*64 + w*16 +
  // it*4 + g for chunk c, step it.
  const v4i* Ah = (const v4i*)xh + n * 256 + w * 16 + g;
  const v4i* Al = (const v4i*)xl + n * 256 + w * 16 + g;

  v4i wr_[4][4];   // [sub i][row r]
#define STAGE_LOAD(c)                                                        \
  {                                                                          \
    _Pragma("unroll") for (int i = 0; i < 4; ++i) {                          \
      wr_[i][0] = Wr0[(c) * 256 + i * 64];                                   \
      wr_[i][1] = Wr1[(c) * 256 + i * 64];                                   \
      wr_[i][2] = Wr2[(c) * 256 + i * 64];                                   \
      wr_[i][3] = Wr3[(c) * 256 + i * 64];                                   \
    }                                                                        \
  }
#define STAGE_WRITE(buf)                                                     \
  {                                                                          \
    uint32_t* wb = wbuf[buf];                                                \
    _Pragma("unroll") for (int i = 0; i < 4; ++i) {                          \
      _Pragma("unroll") for (int r = 0; r < 4; ++r) {                        \
        v4i q = wr_[i][r];                                                   \
        uint32_t p = ((uint32_t)q.x & 0xffu) |                               \
                     (((uint32_t)q.y & 0xffu) << 8) |                        \
                     (((uint32_t)q.z & 0xffu) << 16) |                       \
                     (((uint32_t)q.w & 0xffu) << 24);                        \
        wb[wbase[r] + i * 64] = p;                                           \
      }                                                                      \
    }                                                                        \
  }

  // Prologue: stage chunk 0.
  STAGE_LOAD(0);
  STAGE_WRITE(0);
  asm volatile("s_waitcnt lgkmcnt(0)" ::: "memory");
  __builtin_amdgcn_s_barrier();

  v4i accH = {0, 0, 0, 0};
  v4i accL = {0, 0, 0, 0};

#pragma unroll
  for (int c = 0; c < 4; ++c) {
    const int cur = c & 1;
    if (c + 1 < 4) STAGE_LOAD(c + 1);   // in flight during compute
    // Compute chunk c: 4 x (ds_read_b128 + hi/lo MFMA).
#pragma unroll
    for (int it = 0; it < 4; ++it) {
      const int j = w * 16 + it * 4 + g;   // b128 slot within row
      const v4i b =
          *(const v4i*)&wbuf[cur][n * 256 + ((j ^ (n & 7)) << 2)];
      accH = __builtin_amdgcn_mfma_i32_16x16x64_i8(Ah[c * 64 + it * 4], b,
                                                   accH, 0, 0, 0);
      accL = __builtin_amdgcn_mfma_i32_16x16x64_i8(Al[c * 64 + it * 4], b,
                                                   accL, 0, 0, 0);
    }
    if (c + 1 < 4) STAGE_WRITE(cur ^ 1);  // counted vmcnt inside
    asm volatile("s_waitcnt lgkmcnt(0)" ::: "memory");
    __builtin_amdgcn_s_barrier();
  }

  // C layout (16x16): col = lane&15 (=o), row = (lane>>4)*4 + reg (=token)
#pragma unroll
  for (int r = 0; r < 4; ++r) {
    float f = (float)accH[r] + (float)accL[r] * (1.0f / 256.0f);
    const int t = g * 4 + r;
    red[w][t * 17 + n] = f;
  }
  __syncthreads();

  const int t = tid >> 4;
  const int col = tid & 15;
  const float sum = red[0][t * 17 + col] + red[1][t * 17 + col] +
                    red[2][t * 17 + col] + red[3][t * 17 + col];
  const float sc = scale_p[0];
  const float zp = (float)zp_p[0];
  const float o = sc * (s1[t] * sum) - sc * zp * sumx[t];
  out[(long)t * N_OUT + obase + col] = o;
}

extern "C" void kernel_launch(void* const* d_in, const int* in_sizes, int n_in,
                              void* d_out, int out_size, void* d_ws,
                              size_t ws_size, hipStream_t stream) {
  const float* x = (const float*)d_in[0];
  const int* Wq = (const int*)d_in[1];          // int inputs come as int32
  const float* scale_p = (const float*)d_in[2];
  const int* zp_p = (const int*)d_in[3];
  float* out = (float*)d_out;

  int8_t* xh = (int8_t*)d_ws;
  int8_t* xl = xh + (long)M_TOK * K_DIM;
  float* s1 = (float*)(xl + (long)M_TOK * K_DIM);
  float* sumx = s1 + M_TOK;

  quant_x_kernel<<<M_TOK, 256, 0, stream>>>(x, xh, xl, s1, sumx);
  qgemm_kernel<<<N_OUT / 16, 256, 0, stream>>>(Wq, xh, xl, s1, sumx, scale_p,
                                               zp_p, out);
}